// Round 9
// baseline (400.499 us; speedup 1.0000x reference)
//
#include <hip/hip_runtime.h>

// ---------------------------------------------------------------------------
// SNN forward, split-phase v5.12.
// wsum (parallel over t, LDS-LUT conv / MFMA fc) + scan (serial LIF).
// T16-tiled wsum slabs, sector-perfect register stores.
// v5.12: conv1 channel-PAIR LUT — combined 10-bit window (w0|w1<<5) indexes
// tpair[2 pairings][4 ky][1024] ffrag (128KiB); ky=4 keeps 32-entry tables.
// Gathers per (pixel,t): 20 -> 12 (the measured dominant cost: 54 of 71us
// was LDS-gather pipe). 142.9KB LDS -> 1 block/CU (9 waves; occupancy was
// ~11.6 waves anyway). Pair tables built in-block from small tables.
// Store path + slab layout bit-identical to v5.11.
// v5.11 retained: mb1/2/3 fused into scans; wsplit folded into k_masks;
// wbT coalesced fc1mm staging; no memsets.
// ---------------------------------------------------------------------------

#define THETA 5120.0f

typedef __attribute__((ext_vector_type(8))) short bfrag;   // 8 bf16 (4 VGPRs)
typedef __attribute__((ext_vector_type(4))) float ffrag;   // 4 f32

__device__ __forceinline__ float dyn_step(float x, float& u, float& v, float& r) {
#pragma clang fp contract(off)
    u = 0.75f * u + 64.0f * x;          // current decay (1024/4096), W_SCALE=64
    float vn = 0.96875f * v + u;        // voltage decay (128/4096)
    vn = (r > 0.0f) ? 0.0f : vn;        // refractory clamp
    float s;
    if (vn >= THETA) { s = 1.0f; v = 0.0f; r = 1.0f; }
    else             { s = 0.0f; v = vn; r = fmaxf(r - 1.0f, 0.0f); }
    return s;
}

__device__ __forceinline__ float dpp_add_xor1(float x) {
    int y = __builtin_amdgcn_update_dpp(0, __float_as_int(x), 0xB1, 0xF, 0xF, true);
    return x + __int_as_float(y);
}
__device__ __forceinline__ float dpp_add_xor2(float x) {
    int y = __builtin_amdgcn_update_dpp(0, __float_as_int(x), 0x4E, 0xF, 0xF, true);
    return x + __int_as_float(y);
}

// compress bits at positions 4k (k=0..15) of a 64-bit word into 16 bits
__device__ __forceinline__ unsigned int compress4(unsigned long long x) {
    x &= 0x1111111111111111ull;
    x = (x | (x >> 3))  & 0x0303030303030303ull;
    x = (x | (x >> 6))  & 0x000F000F000F000Full;
    x = (x | (x >> 12)) & 0x000000FF000000FFull;
    x = (x | (x >> 24)) & 0xFFFFull;
    return (unsigned int)x;
}

__device__ __forceinline__ unsigned short f2bf(float f) {
    unsigned int u = __float_as_uint(f);
    unsigned int r = (u + 0x7FFFu + ((u >> 16) & 1u)) >> 16;   // RNE
    return (unsigned short)r;
}
__device__ __forceinline__ float bf2f(unsigned short b) {
    return __uint_as_float(((unsigned int)b) << 16);
}

__device__ __forceinline__ float f4_elem(float4 v, int j) {
    return (j == 0) ? v.x : (j == 1) ? v.y : (j == 2) ? v.z : v.w;
}

// ---------------------------------------------------------------------------
// k_masks: blocks [0,624): in [B=48,C=4,26,26,T=128] f32 -> xb
// uint2[t][b][pr][28 rows]; y==0 waves also zero pad rows 0/27 (memset fold).
// blocks [624,1200): wfc1[512][288] f32 -> wbT[512][864] bf16x3 split.
// ---------------------------------------------------------------------------
__global__ __launch_bounds__(256) void k_masks(const float* __restrict__ in,
                                               const float* __restrict__ wfc1,
                                               uint2* __restrict__ xb,
                                               unsigned short* __restrict__ wb) {
    if (blockIdx.x >= 624) {
        int gid = (blockIdx.x - 624) * 256 + threadIdx.x;   // 0..147455
        int o = gid / 288, k = gid % 288;
        float w = wfc1[gid];
        unsigned short b0 = f2bf(w);
        float r1 = w - bf2f(b0);
        unsigned short b1 = f2bf(r1);
        float r2 = r1 - bf2f(b1);
        unsigned short b2 = f2bf(r2);
        size_t ob = (size_t)o * 864 + k;
        wb[ob]       = b0;
        wb[ob + 288] = b1;
        wb[ob + 576] = b2;
        return;
    }
    int wv = blockIdx.x * 4 + (threadIdx.x >> 6);
    int lane = threadIdx.x & 63;
    int y = wv % 26; int r = wv / 26;
    int pr = r & 1; int b = r >> 1;
    int ch = lane >> 5;
    int x = lane & 31;
    int act = x < 26;
    int xc = act ? x : 25;
    const float4* src = (const float4*)(in + (size_t)(((b * 4 + pr * 2 + ch) * 26 + y) * 26 + xc) * 128);
    uint2* dst = xb + ((size_t)b * 2 + pr) * 28 + (y + 1);
    if (y == 0) {
        uint2* pp = xb + ((size_t)b * 2 + pr) * 28;
        uint2 z = make_uint2(0u, 0u);
#pragma unroll
        for (int h = 0; h < 2; ++h) {
            int t = h * 64 + lane;
            pp[(size_t)t * 2688] = z;
            pp[(size_t)t * 2688 + 27] = z;
        }
    }
    for (int t4 = 0; t4 < 32; ++t4) {
        float4 f = src[t4];
#pragma unroll
        for (int k = 0; k < 4; ++k) {
            float fv = f4_elem(f, k);
            unsigned long long bal = __ballot(act && (fv != 0.0f));
            if (lane == 0) {
                unsigned int lo = ((unsigned int)bal & 0x03FFFFFFu) << 1;
                unsigned int hi = ((unsigned int)(bal >> 32) & 0x03FFFFFFu) << 1;
                dst[(size_t)(t4 * 4 + k) * 2688] = make_uint2(lo, hi);
            }
        }
    }
}

// ---------------------------------------------------------------------------
// k_wsum1: conv1 wsum (4->8ch, 5x5, 26->24), channel-pair LUT (v5.12).
// H = blockIdx&1 selects weights + 56.6MB slab region. Per (pixel,t):
// ky 0..3 use tpair[p][ky][w0|(w1<<5)] (2 pair-gathers/ky = 8), ky=4 uses
// 4 small 32-entry gathers -> 12 gathers total (was 20). LDS 142.9KB ->
// 1 block/CU. Block 576 = one b's pixels (quad-major); t-chunk 8.
// Grid 1536 = 48b x 16tch x 2H. T16-tiled output, v5.5 sector stores.
// ---------------------------------------------------------------------------
__global__ __launch_bounds__(576) void k_wsum1(const uint2* __restrict__ xb,
                                               const float* __restrict__ w1,
                                               float* __restrict__ ws) {
    __shared__ float wsh[400];
    __shared__ ffrag sm[640];             // [ch][5ky][32] float4 (10.2 KB)
    __shared__ ffrag tpair[8192];         // [2p][4ky][1024] float4 (128 KiB)
    int tid = threadIdx.x;
    int H = blockIdx.x & 1;
    int bid = blockIdx.x >> 1;
    int tch = bid & 15;
    int b = bid >> 4;                     // 0..47
    float* wsH = ws + (size_t)H * 14155776;
    if (tid < 400) wsh[tid] = w1[H * 400 + tid];   // [oc4][ch][5][5]
    __syncthreads();
    for (int e = tid; e < 640; e += 576) {
        int ch = e / 160;
        int rem = e % 160;
        int ky = rem / 32;
        int idx = rem % 32;
        ffrag val = {0.f, 0.f, 0.f, 0.f};
#pragma unroll
        for (int oc4 = 0; oc4 < 4; ++oc4) {
            float a = 0.f;
#pragma unroll
            for (int k = 0; k < 5; ++k)
                a += ((idx >> k) & 1) ? wsh[oc4 * 100 + ch * 25 + ky * 5 + k] : 0.f;
            val[oc4] = a;
        }
        sm[ch * 160 + ky * 32 + idx] = val;
    }
    __syncthreads();
    for (int e = tid; e < 8192; e += 576) {
        int p = e >> 12;                  // pairing: 0 = ch0+ch1, 1 = ch2+ch3
        int ky = (e >> 10) & 3;
        int idx = e & 1023;
        int w0 = idx & 31, w1i = idx >> 5;
        tpair[e] = sm[(2 * p) * 160 + ky * 32 + w0] + sm[(2 * p + 1) * 160 + ky * 32 + w1i];
    }
    __syncthreads();
    int q = tid >> 2, s = tid & 3;
    int ox = (q % 12) * 2 + (s & 1);
    int oy = (q / 12) * 2 + (s >> 1);
    int t0 = tch * 8;
    ffrag acc[8];
#pragma unroll
    for (int j = 0; j < 8; ++j) {
        int t = t0 + j;
        const uint2* rp = xb + ((size_t)t * 48 + b) * 56 + oy;
        ffrag a = {0.f, 0.f, 0.f, 0.f};
#pragma unroll
        for (int ky = 0; ky < 4; ++ky) {
            uint2 r0 = rp[ky];
            uint2 r1 = rp[28 + ky];
            int idxA = (int)(((r0.x >> ox) & 31u) | (((r0.y >> ox) & 31u) << 5));
            int idxB = (int)(((r1.x >> ox) & 31u) | (((r1.y >> ox) & 31u) << 5));
            a += tpair[(ky << 10) + idxA];
            a += tpair[(1 << 12) + (ky << 10) + idxB];
        }
        {
            uint2 r0 = rp[4];
            uint2 r1 = rp[28 + 4];
            a += sm[128 + (int)((r0.x >> ox) & 31u)];            // ch0, ky4
            a += sm[160 + 128 + (int)((r0.y >> ox) & 31u)];      // ch1, ky4
            a += sm[320 + 128 + (int)((r1.x >> ox) & 31u)];      // ch2, ky4
            a += sm[480 + 128 + (int)((r1.y >> ox) & 31u)];      // ch3, ky4
        }
        acc[j] = a;
    }
    size_t tilebase = (size_t)(t0 >> 4) * 1769472 + (t0 & 15);
#pragma unroll
    for (int oc4 = 0; oc4 < 4; ++oc4) {
        float* wp = wsH + tilebase + (size_t)((b * 4 + oc4) * 576 + tid) * 16;
        *(float4*)(wp)     = make_float4(acc[0][oc4], acc[1][oc4], acc[2][oc4], acc[3][oc4]);
        *(float4*)(wp + 4) = make_float4(acc[4][oc4], acc[5][oc4], acc[6][oc4], acc[7][oc4]);
    }
}

// ---------------------------------------------------------------------------
// k_scan1: conv1 LIF + pool1 LIF + mb1 epilogue. Block 576 = 9 waves = one
// (H,b,ocl) image: blk = H*192 + (b*4+ocl). Spike words -> LDS sh[sub][t];
// after barrier the block writes pb16 rows (12 bits <<1) + pads directly.
// Grid 384.
// ---------------------------------------------------------------------------
__global__ __launch_bounds__(576) void k_scan1(const float* __restrict__ ws,
                                               unsigned short* __restrict__ pb16) {
    __shared__ unsigned short sh[9 * 128];
    int tid = threadIdx.x;
    int sub = tid >> 6, lane = tid & 63;
    int blk = blockIdx.x;                 // 0..383 = H*192 + (b*4+ocl)
    int H = (blk >= 192) ? 1 : 0;
    int ibl = blk - H * 192;              // b*4+ocl
    int b = ibl >> 2, ocl = ibl & 3;
    int oc = H * 4 + ocl;
    const float* bp = ws + (size_t)H * 14155776 + (size_t)((ibl * 9 + sub) * 64 + lane) * 16;
    float u = 0.f, v = 0.f, rf = 0.f;
    float pu = 0.f, pv = 0.f, prf = 0.f;
    float sp = 0.f;
    unsigned int mb[4];
    float4 cur[4], nxt[4];
#pragma unroll
    for (int i = 0; i < 4; ++i) cur[i] = *(const float4*)(bp + i * 4);
    for (int tb = 0; tb < 8; ++tb) {
        if (tb < 7) {
            const float* np = bp + (size_t)(tb + 1) * 1769472;
#pragma unroll
            for (int i = 0; i < 4; ++i) nxt[i] = *(const float4*)(np + i * 4);
        }
#pragma unroll
        for (int j = 0; j < 16; ++j) {
            int t = tb * 16 + j;
            float w = f4_elem(cur[j >> 2], j & 3);
            float cnt = dpp_add_xor2(dpp_add_xor1(sp));
            float ps = dyn_step(88.0f * cnt, pu, pv, prf);
            unsigned long long bal = __ballot(((lane & 3) == 0) && (ps > 0.5f));
            unsigned int m = compress4(bal);
            int sl = (t >> 1) & 3;
            mb[sl] = (t & 1) ? (mb[sl] | (m << 16)) : m;
            if ((t & 7) == 7 && lane == 0)
                *(uint4*)(&sh[sub * 128 + (t & ~7)]) = make_uint4(mb[0], mb[1], mb[2], mb[3]);
            sp = dyn_step(w, u, v, rf);
        }
        if (tb < 7) {
#pragma unroll
            for (int i = 0; i < 4; ++i) cur[i] = nxt[i];
        }
    }
    __syncthreads();
    // mb1 epilogue: 128 t x 12 y rows for this (b,oc)
    for (int idx = tid; idx < 1536; idx += 576) {
        int t = idx / 12, y = idx % 12;
        int Q0 = y * 12;
        int w0 = Q0 >> 4, off = Q0 & 15;
        unsigned int v0 = sh[w0 * 128 + t];
        unsigned int v1 = (off > 4) ? (unsigned int)sh[(w0 + 1) * 128 + t] : 0u;
        unsigned int m = ((v0 >> off) | (v1 << (16 - off))) & 0xFFFu;
        size_t rowb = (size_t)(t * 48 + b) * 14;
        pb16[(rowb + y + 1) * 8 + oc] = (unsigned short)(m << 1);
        if (y == 0)  pb16[rowb * 8 + oc] = 0;
        if (y == 11) pb16[(rowb + 13) * 8 + oc] = 0;
    }
}

// ---------------------------------------------------------------------------
// k_wsum2: conv2 wsum (8->16ch, 3x3, 12->12), oc-quad vectorized.
// Pair 6-bit windows -> float4 LUT over the oc quad: tbl4[(pr*3+ky)*71+idx]
// (13.6 KB). Block = (b, ocg, tch): 576 thr = 4 tq x 144 pix; one thread =
// one pixel, 4 oc, 8 t. Grid 768 = 48b x 4ocg x 4tch. T16-tiled output.
// ---------------------------------------------------------------------------
__global__ __launch_bounds__(576) void k_wsum2(const unsigned short* __restrict__ pb16,
                                               const float* __restrict__ w2,
                                               float* __restrict__ ws) {
    __shared__ float wsh[288];
    __shared__ ffrag tbl4[852];           // [4pr][3ky][71] float4 (13.6 KB)
    int tid = threadIdx.x;
    int tch = blockIdx.x & 3;
    int r = blockIdx.x >> 2;
    int ocg = r & 3; int b = r >> 2;      // b 0..47, ocg 0..3
    if (tid < 288) wsh[tid] = w2[(ocg * 4 + tid / 72) * 72 + (tid % 72)];
    __syncthreads();
    for (int e = tid; e < 852; e += 576) {
        int pr = e / 213;                 // 3*71
        int rem = e % 213;
        int ky = rem / 71;
        int idx = rem % 71;
        int lo = idx % 9, hi = idx / 9;   // valid windows have lo<8, hi<8
        ffrag val = {0.f, 0.f, 0.f, 0.f};
#pragma unroll
        for (int oc4 = 0; oc4 < 4; ++oc4) {
            float a = 0.f;
#pragma unroll
            for (int k = 0; k < 3; ++k)
                a += ((lo >> k) & 1) ? wsh[oc4 * 72 + (2 * pr) * 9 + ky * 3 + k] : 0.f;
#pragma unroll
            for (int k = 0; k < 3; ++k)
                a += ((hi >> k) & 1) ? wsh[oc4 * 72 + (2 * pr + 1) * 9 + ky * 3 + k] : 0.f;
            val[oc4] = a;
        }
        tbl4[(pr * 3 + ky) * 71 + idx] = val;
    }
    __syncthreads();
    int tq = tid / 144;
    int pix = tid % 144;
    int q = pix >> 2, s = pix & 3;
    int ox = (q % 6) * 2 + (s & 1);
    int oy = (q / 6) * 2 + (s >> 1);
    int t0 = tch * 32 + tq * 8;
    ffrag acc[8];
#pragma unroll
    for (int j = 0; j < 8; ++j) {
        int t = t0 + j;
        ffrag a = {0.f, 0.f, 0.f, 0.f};
        if (t > 0) {
            const uint4* rp = (const uint4*)(pb16 + (((size_t)(t - 1) * 48 + b) * 14 + oy) * 8);
#pragma unroll
            for (int ky = 0; ky < 3; ++ky) {
                uint4 row = rp[ky];
                unsigned int wd[4] = {row.x, row.y, row.z, row.w};
#pragma unroll
                for (int pr = 0; pr < 4; ++pr) {
                    unsigned int lo = (wd[pr] >> ox) & 7u;
                    unsigned int hi = (wd[pr] >> (16 + ox)) & 7u;
                    a += tbl4[(pr * 3 + ky) * 71 + (int)(lo + 9u * hi)];
                }
            }
        }
        acc[j] = a;
    }
    size_t tilebase = (size_t)(t0 >> 4) * 1769472 + (t0 & 15);
#pragma unroll
    for (int oc4 = 0; oc4 < 4; ++oc4) {
        int neuron = (b * 16 + ocg * 4 + oc4) * 144 + pix;
        float* wp = ws + tilebase + (size_t)neuron * 16;
        *(float4*)(wp)     = make_float4(acc[0][oc4], acc[1][oc4], acc[2][oc4], acc[3][oc4]);
        *(float4*)(wp + 4) = make_float4(acc[4][oc4], acc[5][oc4], acc[6][oc4], acc[7][oc4]);
    }
}

// ---------------------------------------------------------------------------
// k_scan2: conv2 LIF + pool2 LIF + mb2 epilogue. Block 576 = 4 images
// (9 waves); wave = 16 quads. Spike words -> LDS sh[wloc][t]; after barrier
// block writes pb2 rows (6 bits <<1) + pads for its 4 images. Grid 192.
// ---------------------------------------------------------------------------
__global__ __launch_bounds__(576) void k_scan2(const float* __restrict__ ws,
                                               unsigned short* __restrict__ pb2) {
    __shared__ unsigned short sh[9 * 128];
    int tid = threadIdx.x;
    int wloc = tid >> 6, lane = tid & 63;
    int g4 = blockIdx.x;                  // 0..191
    const float* bp = ws + (size_t)(g4 * 576 + tid) * 16;
    float u = 0.f, v = 0.f, rf = 0.f;
    float pu = 0.f, pv = 0.f, prf = 0.f;
    float sp = 0.f;
    unsigned int mb[4];
    float4 cur[4], nxt[4];
#pragma unroll
    for (int i = 0; i < 4; ++i) cur[i] = *(const float4*)(bp + i * 4);
    for (int tb = 0; tb < 8; ++tb) {
        if (tb < 7) {
            const float* np = bp + (size_t)(tb + 1) * 1769472;
#pragma unroll
            for (int i = 0; i < 4; ++i) nxt[i] = *(const float4*)(np + i * 4);
        }
#pragma unroll
        for (int j = 0; j < 16; ++j) {
            int t = tb * 16 + j;
            float w = f4_elem(cur[j >> 2], j & 3);
            float cnt = dpp_add_xor2(dpp_add_xor1(sp));
            float ps = dyn_step(88.0f * cnt, pu, pv, prf);
            unsigned long long bal = __ballot(((lane & 3) == 0) && (ps > 0.5f));
            unsigned int m = compress4(bal);
            int sl = (t >> 1) & 3;
            mb[sl] = (t & 1) ? (mb[sl] | (m << 16)) : m;
            if ((t & 7) == 7 && lane == 0)
                *(uint4*)(&sh[wloc * 128 + (t & ~7)]) = make_uint4(mb[0], mb[1], mb[2], mb[3]);
            sp = dyn_step(w, u, v, rf);
        }
        if (tb < 7) {
#pragma unroll
            for (int i = 0; i < 4; ++i) cur[i] = nxt[i];
        }
    }
    __syncthreads();
    // mb2 epilogue: 128 t x 4 images x 6 y rows
    for (int idx = tid; idx < 3072; idx += 576) {
        int t = idx / 24;
        int r2 = idx % 24;
        int lI = r2 / 6, y = r2 % 6;
        int img = g4 * 4 + lI;
        int b = img >> 4, oc = img & 15;
        int Q0 = lI * 36 + y * 6;
        int w0 = Q0 >> 4, off = Q0 & 15;
        unsigned int v0 = sh[w0 * 128 + t];
        unsigned int v1 = (off > 10) ? (unsigned int)sh[(w0 + 1) * 128 + t] : 0u;
        unsigned int m = ((v0 >> off) | (v1 << (16 - off))) & 0x3Fu;
        size_t rowb = (size_t)(t * 48 + b) * 8;
        pb2[(rowb + y + 1) * 16 + oc] = (unsigned short)(m << 1);
        if (y == 0) pb2[rowb * 16 + oc] = 0;
        if (y == 5) pb2[(rowb + 7) * 16 + oc] = 0;
    }
}

// ---------------------------------------------------------------------------
// k_wsum3: conv3 wsum (16->32ch, 3x3, 6->6), oc-quad vectorized.
// Pair 6-bit windows -> float4 LUT over the oc quad: tbl4[(pr*3+ky)*71+idx]
// (8 pr, 27.3 KB). Block = (ocg, bg, tch): 576 thr = 4 bsel x 36 pix x 4 tq;
// one thread = one pixel, 4 oc, 4 t. tq innermost -> 4-lane groups write
// full 64B sectors. Grid 768 = 8ocg x 12bg x 8tch. T16-tiled output.
// ---------------------------------------------------------------------------
__global__ __launch_bounds__(576) void k_wsum3(const unsigned short* __restrict__ pb2,
                                               const float* __restrict__ w3,
                                               float* __restrict__ ws) {
    __shared__ float wsh[576];
    __shared__ ffrag tbl4[1704];          // [8pr][3ky][71] float4 (27.3 KB)
    int tid = threadIdx.x;
    int tch = blockIdx.x & 7;
    int gb = blockIdx.x >> 3;             // 0..95 = ocg*12 + bg
    int ocg = gb / 12, bg = gb % 12;
    wsh[tid] = w3[(ocg * 4 + tid / 144) * 144 + (tid % 144)];
    __syncthreads();
    for (int e = tid; e < 1536; e += 576) {
        int pr = e / 192;                 // 0..7
        int ky = (e / 64) % 3;
        int i = e & 63;
        int lo = i & 7, hi = i >> 3;
        ffrag val = {0.f, 0.f, 0.f, 0.f};
#pragma unroll
        for (int oc4 = 0; oc4 < 4; ++oc4) {
            float a = 0.f;
#pragma unroll
            for (int k = 0; k < 3; ++k)
                a += ((lo >> k) & 1) ? wsh[oc4 * 144 + (2 * pr) * 9 + ky * 3 + k] : 0.f;
#pragma unroll
            for (int k = 0; k < 3; ++k)
                a += ((hi >> k) & 1) ? wsh[oc4 * 144 + (2 * pr + 1) * 9 + ky * 3 + k] : 0.f;
            val[oc4] = a;
        }
        tbl4[(pr * 3 + ky) * 71 + lo + 9 * hi] = val;
    }
    __syncthreads();
    int tq = tid & 3;
    int r = tid >> 2;                     // 0..143
    int pix = r % 36;
    int bsel = r / 36;                    // 0..3
    int q = pix >> 2, s = pix & 3;
    int ox = (q % 3) * 2 + (s & 1);
    int oy = (q / 3) * 2 + (s >> 1);
    int b = bg * 4 + bsel;
    int t0 = tch * 16 + tq * 4;
    ffrag acc[4];
#pragma unroll
    for (int j = 0; j < 4; ++j) {
        int t = t0 + j;
        ffrag a = {0.f, 0.f, 0.f, 0.f};
        if (t > 0) {
            const uint4* rp = (const uint4*)(pb2 + (((size_t)(t - 1) * 48 + b) * 8 + oy) * 16);
#pragma unroll
            for (int ky = 0; ky < 3; ++ky) {
                uint4 rA = rp[ky * 2];
                uint4 rB = rp[ky * 2 + 1];
                unsigned int wd[8] = {rA.x, rA.y, rA.z, rA.w, rB.x, rB.y, rB.z, rB.w};
#pragma unroll
                for (int pr = 0; pr < 8; ++pr) {
                    unsigned int lo = (wd[pr] >> ox) & 7u;
                    unsigned int hi = (wd[pr] >> (16 + ox)) & 7u;
                    a += tbl4[(pr * 3 + ky) * 71 + (int)(lo + 9u * hi)];
                }
            }
        }
        acc[j] = a;
    }
    size_t base = (size_t)tch * 884736;
#pragma unroll
    for (int oc4 = 0; oc4 < 4; ++oc4) {
        int neuron = (b * 32 + ocg * 4 + oc4) * 36 + pix;
        float* wp = ws + base + (size_t)neuron * 16 + tq * 4;
        *(float4*)(wp) = make_float4(acc[0][oc4], acc[1][oc4], acc[2][oc4], acc[3][oc4]);
    }
}

// ---------------------------------------------------------------------------
// k_scan3: conv3 LIF + pool3 LIF + mb3 epilogue. Block 256 = 4 waves
// covering G range [blockIdx*64, +64). Spike words -> LDS sh[wloc][t]; after
// barrier block writes a3 bf16 rows (t+1, delay-shift folded) + zeroes its
// slice of row 0. Grid 216.
// ---------------------------------------------------------------------------
__global__ __launch_bounds__(256) void k_scan3(const float* __restrict__ ws,
                                               unsigned short* __restrict__ a3) {
    __shared__ unsigned short sh[4 * 128];
    int tid = threadIdx.x;
    int wloc = tid >> 6, lane = tid & 63;
    int wv = blockIdx.x * 4 + wloc;       // 0..863
    const float* bp = ws + (size_t)(wv * 64 + lane) * 16;
    float u = 0.f, v = 0.f, rf = 0.f;
    float pu = 0.f, pv = 0.f, prf = 0.f;
    float sp = 0.f;
    unsigned int mb[4];
    float4 cur[4], nxt[4];
#pragma unroll
    for (int i = 0; i < 4; ++i) cur[i] = *(const float4*)(bp + i * 4);
    for (int tb = 0; tb < 8; ++tb) {
        if (tb < 7) {
            const float* np = bp + (size_t)(tb + 1) * 884736;
#pragma unroll
            for (int i = 0; i < 4; ++i) nxt[i] = *(const float4*)(np + i * 4);
        }
#pragma unroll
        for (int j = 0; j < 16; ++j) {
            int t = tb * 16 + j;
            float w = f4_elem(cur[j >> 2], j & 3);
            float cnt = dpp_add_xor2(dpp_add_xor1(sp));
            float ps = dyn_step(88.0f * cnt, pu, pv, prf);
            unsigned long long bal = __ballot(((lane & 3) == 0) && (ps > 0.5f));
            unsigned int m = compress4(bal);
            int sl = (t >> 1) & 3;
            mb[sl] = (t & 1) ? (mb[sl] | (m << 16)) : m;
            if ((t & 7) == 7 && lane == 0)
                *(uint4*)(&sh[wloc * 128 + (t & ~7)]) = make_uint4(mb[0], mb[1], mb[2], mb[3]);
            sp = dyn_step(w, u, v, rf);
        }
        if (tb < 7) {
#pragma unroll
            for (int i = 0; i < 4; ++i) cur[i] = nxt[i];
        }
    }
    __syncthreads();
    // mb3 epilogue: G slice [blockIdx*64, +64), rows t+1 for t in [0,127)
    int G0 = blockIdx.x * 64;
    int g = tid & 63, tq = tid >> 6;
    if (tq == 0) a3[G0 + g] = 0;          // row 0 (delay-shift zero)
    for (int t = tq; t < 127; t += 4) {
        unsigned int bit = ((unsigned int)sh[(g >> 4) * 128 + t] >> (g & 15)) & 1u;
        a3[(size_t)(t + 1) * 13824 + G0 + g] = bit ? 0x3F80 : 0;
    }
}

// ---------------------------------------------------------------------------
// k_fc1mm: wsf1[m][o] = A x W via mfma_f32_16x16x32_bf16. Linear coalesced
// epilogue (wsf1[m*512+n]). Bs staging reads transposed wbT[512][864].
// ---------------------------------------------------------------------------
__global__ __launch_bounds__(256) void k_fc1mm(const unsigned short* __restrict__ a3,
                                               const unsigned short* __restrict__ wb,
                                               float* __restrict__ wsf1) {
    __shared__ unsigned short Bs[16 * 872];
    int tid = threadIdx.x;
    int nt = blockIdx.x & 31;
    int mc = blockIdx.x >> 5;
    int n0 = nt * 16;
    for (int idx = tid; idx < 13824; idx += 256) {
        int n = idx / 864;
        int kp = idx % 864;
        Bs[n * 872 + kp] = wb[(size_t)(n0 + n) * 864 + kp];
    }
    __syncthreads();
    int wave = tid >> 6;
    int lane = tid & 63;
    int ln = lane & 15, quad = lane >> 4;
#pragma unroll
    for (int i = 0; i < 4; ++i) {
        int m0 = (mc * 16 + wave * 4 + i) * 16;
        const unsigned short* arow = a3 + (size_t)(m0 + ln) * 288 + quad * 8;
        ffrag acc = {0.f, 0.f, 0.f, 0.f};
#pragma unroll
        for (int kb = 0; kb < 9; ++kb) {
            bfrag av = *(const bfrag*)(arow + kb * 32);
#pragma unroll
            for (int c = 0; c < 3; ++c) {
                bfrag bv = *(const bfrag*)(&Bs[ln * 872 + c * 288 + kb * 32 + quad * 8]);
                acc = __builtin_amdgcn_mfma_f32_16x16x32_bf16(av, bv, acc, 0, 0, 0);
            }
        }
        float* wout = wsf1 + (size_t)(m0 + quad * 4) * 512 + n0 + ln;
        wout[0] = acc[0];
        wout[512] = acc[1];
        wout[1024] = acc[2];
        wout[1536] = acc[3];
    }
}

// k_fc1s: fc1 LIF scan, linear strided reads + 16-deep prefetch.
__global__ __launch_bounds__(256) void k_fc1s(const float* __restrict__ wsf1,
                                              float* __restrict__ f1f) {
    int tid = blockIdx.x * 256 + threadIdx.x;   // 0..24575
    float u = 0.f, v = 0.f, rf = 0.f;
    float wbuf[16];
#pragma unroll
    for (int i = 0; i < 16; ++i) wbuf[i] = wsf1[(size_t)i * 24576 + tid];
    for (int tb = 0; tb < 128; tb += 16) {
#pragma unroll
        for (int j = 0; j < 16; ++j) {
            int t = tb + j;
            float w = wbuf[j];
            if (t + 16 < 128) wbuf[j] = wsf1[(size_t)(t + 16) * 24576 + tid];
            float s = dyn_step(w, u, v, rf);
            f1f[(size_t)t * 24576 + tid] = s;
        }
    }
}

// k_fc2w: fc2 wsum, parallel over t. Wave per (t,b).
__global__ __launch_bounds__(256) void k_fc2w(const float* __restrict__ f1f,
                                              const float* __restrict__ wfc2,
                                              float* __restrict__ wsf2) {
    int wv = blockIdx.x * 4 + (threadIdx.x >> 6);   // 0..6143
    int lane = threadIdx.x & 63;
    int b = wv % 48, t = wv / 48;
    int o = lane & 1, kq = lane >> 1;
    float acc = 0.f;
    if (t > 0) {
        const float* wp = wfc2 + o * 512 + kq * 16;
        const float* sp = f1f + (size_t)(t - 1) * 24576 + b * 512 + kq * 16;
#pragma unroll
        for (int i = 0; i < 16; ++i) acc += wp[i] * sp[i];
    }
#pragma unroll
    for (int m = 2; m < 64; m <<= 1) acc += __shfl_xor(acc, m, 64);
    if (lane < 2) wsf2[(size_t)t * 96 + b * 2 + o] = acc;
}

// k_fc2s: fc2 LIF scan + delay-shift into out [B,2,T]. 96 active threads.
__global__ __launch_bounds__(128) void k_fc2s(const float* __restrict__ wsf2,
                                              float* __restrict__ out) {
    int tid = threadIdx.x;
    if (tid >= 96) return;
    float* ob = out + tid * 128;       // tid = b*2+o
    ob[0] = 0.0f;
    float u = 0.f, v = 0.f, rf = 0.f;
    float wbuf[8];
#pragma unroll
    for (int i = 0; i < 8; ++i) wbuf[i] = wsf2[(size_t)i * 96 + tid];
    for (int tb = 0; tb < 128; tb += 8) {
#pragma unroll
        for (int j = 0; j < 8; ++j) {
            int t = tb + j;
            float w = wbuf[j];
            if (t + 8 < 128) wbuf[j] = wsf2[(size_t)(t + 8) * 96 + tid];
            float s = dyn_step(w, u, v, rf);
            if (t < 127) ob[t + 1] = s;
        }
    }
}

// ---------------------------------------------------------------------------
extern "C" void kernel_launch(void* const* d_in, const int* in_sizes, int n_in,
                              void* d_out, int out_size, void* d_ws, size_t ws_size,
                              hipStream_t stream) {
    const float* in   = (const float*)d_in[0];
    const float* w1   = (const float*)d_in[1];
    const float* w2   = (const float*)d_in[2];
    const float* w3   = (const float*)d_in[3];
    const float* wfc1 = (const float*)d_in[4];
    const float* wfc2 = (const float*)d_in[5];
    float* out = (float*)d_out;
    char* ws = (char*)d_ws;

    float*          slab = (float*)(ws);                       // 113,246,208 (conv1 2-half slab; conv2/3 use region 0)
    uint2*          xb   = (uint2*)(ws + 113246208);           //  2,752,512
    unsigned short* pb16 = (unsigned short*)(ws + 115998720);  //  1,376,256
    unsigned short* pb2  = (unsigned short*)(ws + 117374976);  //  1,572,864
    float*          f1f  = (float*)(ws + 118947840);           // 12,582,912
    unsigned short* a3   = (unsigned short*)(ws + 131530752);  //  3,538,944 [128][13824] bf16
    unsigned short* wb   = (unsigned short*)(ws + 135069696);  //    884,736 wbT[512][864] bf16
    float*          wsf1 = (float*)(ws);                       // 12,582,912 (slab reuse, post-scan3)
    float*          wsf2 = (float*)(ws + 16777216);            //     49,152 (slab reuse, disjoint)
    // total 135,954,432 bytes (workspace 256 MiB)
    // no memsets — pad rows written by k_masks / scan epilogues

    k_masks   <<<1200, 256, 0, stream>>>(in, wfc1, xb, wb);   // masks + wsplit fold
    k_wsum1   <<<1536, 576, 0, stream>>>(xb, w1, slab);
    k_scan1   <<<384, 576, 0, stream>>>(slab, pb16);          // + mb1 fold
    k_wsum2   <<<768, 576, 0, stream>>>(pb16, w2, slab);
    k_scan2   <<<192, 576, 0, stream>>>(slab, pb2);           // + mb2 fold
    k_wsum3   <<<768, 576, 0, stream>>>(pb2, w3, slab);
    k_scan3   <<<216, 256, 0, stream>>>(slab, a3);            // + mb3 fold
    k_fc1mm   <<<768, 256, 0, stream>>>(a3, wb, wsf1);
    k_fc1s    <<<96, 256, 0, stream>>>(wsf1, f1f);
    k_fc2w    <<<1536, 256, 0, stream>>>(f1f, wfc2, wsf2);
    k_fc2s    <<<1, 128, 0, stream>>>(wsf2, out);
}

// Round 10
// 369.454 us; speedup vs baseline: 1.0840x; 1.0840x over previous
//
#include <hip/hip_runtime.h>

// ---------------------------------------------------------------------------
// SNN forward, split-phase v5.13 (= v5.11 exactly).
// wsum (parallel over t, LDS-LUT conv / MFMA fc) + scan (serial LIF).
// T16-tiled wsum slabs, sector-perfect register stores.
// v5.13: conv1 wsum REVERTED to v5.11's small-table form. v5.12's
// channel-pair LUT (gathers 20->12) FAILED: 1024-entry pair tables have
// high index entropy -> distinct-address same-bank collisions, conflicts
// 6.6M->15.5M, 71->99us. Small tables win on BROADCAST probability
// (neighboring pixels share windows -> same-address reads are free), not
// just footprint. conv1 inner loop is at its local optimum (~71us,
// ~76% LDS-pipe incl. broadcast) after 3 failed structural attempts.
// v5.11 retained: mb1/2/3 fused into scans (st buffers deleted); wsplit
// folded into k_masks; wbT[512][864] coalesced fc1mm staging; conv1 both
// halves in one wsum1/scan1 launch (per-half 56.6MB slab); no memsets.
// ---------------------------------------------------------------------------

#define THETA 5120.0f

typedef __attribute__((ext_vector_type(8))) short bfrag;   // 8 bf16 (4 VGPRs)
typedef __attribute__((ext_vector_type(4))) float ffrag;   // 4 f32

__device__ __forceinline__ float dyn_step(float x, float& u, float& v, float& r) {
#pragma clang fp contract(off)
    u = 0.75f * u + 64.0f * x;          // current decay (1024/4096), W_SCALE=64
    float vn = 0.96875f * v + u;        // voltage decay (128/4096)
    vn = (r > 0.0f) ? 0.0f : vn;        // refractory clamp
    float s;
    if (vn >= THETA) { s = 1.0f; v = 0.0f; r = 1.0f; }
    else             { s = 0.0f; v = vn; r = fmaxf(r - 1.0f, 0.0f); }
    return s;
}

__device__ __forceinline__ float dpp_add_xor1(float x) {
    int y = __builtin_amdgcn_update_dpp(0, __float_as_int(x), 0xB1, 0xF, 0xF, true);
    return x + __int_as_float(y);
}
__device__ __forceinline__ float dpp_add_xor2(float x) {
    int y = __builtin_amdgcn_update_dpp(0, __float_as_int(x), 0x4E, 0xF, 0xF, true);
    return x + __int_as_float(y);
}

// compress bits at positions 4k (k=0..15) of a 64-bit word into 16 bits
__device__ __forceinline__ unsigned int compress4(unsigned long long x) {
    x &= 0x1111111111111111ull;
    x = (x | (x >> 3))  & 0x0303030303030303ull;
    x = (x | (x >> 6))  & 0x000F000F000F000Full;
    x = (x | (x >> 12)) & 0x000000FF000000FFull;
    x = (x | (x >> 24)) & 0xFFFFull;
    return (unsigned int)x;
}

__device__ __forceinline__ unsigned short f2bf(float f) {
    unsigned int u = __float_as_uint(f);
    unsigned int r = (u + 0x7FFFu + ((u >> 16) & 1u)) >> 16;   // RNE
    return (unsigned short)r;
}
__device__ __forceinline__ float bf2f(unsigned short b) {
    return __uint_as_float(((unsigned int)b) << 16);
}

__device__ __forceinline__ float f4_elem(float4 v, int j) {
    return (j == 0) ? v.x : (j == 1) ? v.y : (j == 2) ? v.z : v.w;
}

// ---------------------------------------------------------------------------
// k_masks: blocks [0,624): in [B=48,C=4,26,26,T=128] f32 -> xb
// uint2[t][b][pr][28 rows]; y==0 waves also zero pad rows 0/27 (memset fold).
// blocks [624,1200): wfc1[512][288] f32 -> wbT[512][864] bf16x3 split.
// ---------------------------------------------------------------------------
__global__ __launch_bounds__(256) void k_masks(const float* __restrict__ in,
                                               const float* __restrict__ wfc1,
                                               uint2* __restrict__ xb,
                                               unsigned short* __restrict__ wb) {
    if (blockIdx.x >= 624) {
        int gid = (blockIdx.x - 624) * 256 + threadIdx.x;   // 0..147455
        int o = gid / 288, k = gid % 288;
        float w = wfc1[gid];
        unsigned short b0 = f2bf(w);
        float r1 = w - bf2f(b0);
        unsigned short b1 = f2bf(r1);
        float r2 = r1 - bf2f(b1);
        unsigned short b2 = f2bf(r2);
        size_t ob = (size_t)o * 864 + k;
        wb[ob]       = b0;
        wb[ob + 288] = b1;
        wb[ob + 576] = b2;
        return;
    }
    int wv = blockIdx.x * 4 + (threadIdx.x >> 6);
    int lane = threadIdx.x & 63;
    int y = wv % 26; int r = wv / 26;
    int pr = r & 1; int b = r >> 1;
    int ch = lane >> 5;
    int x = lane & 31;
    int act = x < 26;
    int xc = act ? x : 25;
    const float4* src = (const float4*)(in + (size_t)(((b * 4 + pr * 2 + ch) * 26 + y) * 26 + xc) * 128);
    uint2* dst = xb + ((size_t)b * 2 + pr) * 28 + (y + 1);
    if (y == 0) {
        uint2* pp = xb + ((size_t)b * 2 + pr) * 28;
        uint2 z = make_uint2(0u, 0u);
#pragma unroll
        for (int h = 0; h < 2; ++h) {
            int t = h * 64 + lane;
            pp[(size_t)t * 2688] = z;
            pp[(size_t)t * 2688 + 27] = z;
        }
    }
    for (int t4 = 0; t4 < 32; ++t4) {
        float4 f = src[t4];
#pragma unroll
        for (int k = 0; k < 4; ++k) {
            float fv = f4_elem(f, k);
            unsigned long long bal = __ballot(act && (fv != 0.0f));
            if (lane == 0) {
                unsigned int lo = ((unsigned int)bal & 0x03FFFFFFu) << 1;
                unsigned int hi = ((unsigned int)(bal >> 32) & 0x03FFFFFFu) << 1;
                dst[(size_t)(t4 * 4 + k) * 2688] = make_uint2(lo, hi);
            }
        }
    }
}

// ---------------------------------------------------------------------------
// k_wsum1: conv1 wsum (4->8ch, 5x5, 26->24), both oc-quad halves in one
// launch. H = blockIdx&1 selects weights + 56.6MB slab region; inner loop
// bit-identical to v5.5 (small 33-entry tables, broadcast-friendly).
// Block 576 = one b's pixels (quad-major); t-chunk 8.
// Grid 1536 = 48b x 16tch x 2H. T16-tiled output, sector stores.
// ---------------------------------------------------------------------------
__global__ __launch_bounds__(576) void k_wsum1(const uint2* __restrict__ xb,
                                               const float* __restrict__ w1,
                                               float* __restrict__ ws) {
    __shared__ float wsh[400];
    __shared__ ffrag tbl4[660];           // [4ch][5ky][33] float4 (10.6 KB)
    int tid = threadIdx.x;
    int H = blockIdx.x & 1;
    int bid = blockIdx.x >> 1;
    int tch = bid & 15;
    int b = bid >> 4;                     // 0..47
    float* wsH = ws + (size_t)H * 14155776;
    if (tid < 400) wsh[tid] = w1[H * 400 + tid];   // [oc4][ch][5][5]
    __syncthreads();
    for (int e = tid; e < 660; e += 576) {
        int ch = e / 165;
        int rem = e % 165;
        int ky = rem / 33;
        int idx = rem % 33;
        ffrag val = {0.f, 0.f, 0.f, 0.f};
#pragma unroll
        for (int oc4 = 0; oc4 < 4; ++oc4) {
            float a = 0.f;
#pragma unroll
            for (int k = 0; k < 5; ++k)
                a += ((idx >> k) & 1) ? wsh[oc4 * 100 + ch * 25 + ky * 5 + k] : 0.f;
            val[oc4] = a;
        }
        tbl4[(ch * 5 + ky) * 33 + idx] = val;
    }
    __syncthreads();
    int q = tid >> 2, s = tid & 3;
    int ox = (q % 12) * 2 + (s & 1);
    int oy = (q / 12) * 2 + (s >> 1);
    int t0 = tch * 8;
    ffrag acc[8];
#pragma unroll
    for (int j = 0; j < 8; ++j) {
        int t = t0 + j;
        const uint2* rp = xb + ((size_t)t * 48 + b) * 56 + oy;
        ffrag a = {0.f, 0.f, 0.f, 0.f};
#pragma unroll
        for (int ky = 0; ky < 5; ++ky) {
            uint2 r0 = rp[ky];
            uint2 r1 = rp[28 + ky];
            a += tbl4[ky * 33 + (int)((r0.x >> ox) & 31u)];
            a += tbl4[(5 + ky) * 33 + (int)((r0.y >> ox) & 31u)];
            a += tbl4[(10 + ky) * 33 + (int)((r1.x >> ox) & 31u)];
            a += tbl4[(15 + ky) * 33 + (int)((r1.y >> ox) & 31u)];
        }
        acc[j] = a;
    }
    size_t tilebase = (size_t)(t0 >> 4) * 1769472 + (t0 & 15);
#pragma unroll
    for (int oc4 = 0; oc4 < 4; ++oc4) {
        float* wp = wsH + tilebase + (size_t)((b * 4 + oc4) * 576 + tid) * 16;
        *(float4*)(wp)     = make_float4(acc[0][oc4], acc[1][oc4], acc[2][oc4], acc[3][oc4]);
        *(float4*)(wp + 4) = make_float4(acc[4][oc4], acc[5][oc4], acc[6][oc4], acc[7][oc4]);
    }
}

// ---------------------------------------------------------------------------
// k_scan1: conv1 LIF + pool1 LIF + mb1 epilogue. Block 576 = 9 waves = one
// (H,b,ocl) image: blk = H*192 + (b*4+ocl). Spike words -> LDS sh[sub][t];
// after barrier the block writes pb16 rows (12 bits <<1) + pads directly.
// Grid 384.
// ---------------------------------------------------------------------------
__global__ __launch_bounds__(576) void k_scan1(const float* __restrict__ ws,
                                               unsigned short* __restrict__ pb16) {
    __shared__ unsigned short sh[9 * 128];
    int tid = threadIdx.x;
    int sub = tid >> 6, lane = tid & 63;
    int blk = blockIdx.x;                 // 0..383 = H*192 + (b*4+ocl)
    int H = (blk >= 192) ? 1 : 0;
    int ibl = blk - H * 192;              // b*4+ocl
    int b = ibl >> 2, ocl = ibl & 3;
    int oc = H * 4 + ocl;
    const float* bp = ws + (size_t)H * 14155776 + (size_t)((ibl * 9 + sub) * 64 + lane) * 16;
    float u = 0.f, v = 0.f, rf = 0.f;
    float pu = 0.f, pv = 0.f, prf = 0.f;
    float sp = 0.f;
    unsigned int mb[4];
    float4 cur[4], nxt[4];
#pragma unroll
    for (int i = 0; i < 4; ++i) cur[i] = *(const float4*)(bp + i * 4);
    for (int tb = 0; tb < 8; ++tb) {
        if (tb < 7) {
            const float* np = bp + (size_t)(tb + 1) * 1769472;
#pragma unroll
            for (int i = 0; i < 4; ++i) nxt[i] = *(const float4*)(np + i * 4);
        }
#pragma unroll
        for (int j = 0; j < 16; ++j) {
            int t = tb * 16 + j;
            float w = f4_elem(cur[j >> 2], j & 3);
            float cnt = dpp_add_xor2(dpp_add_xor1(sp));
            float ps = dyn_step(88.0f * cnt, pu, pv, prf);
            unsigned long long bal = __ballot(((lane & 3) == 0) && (ps > 0.5f));
            unsigned int m = compress4(bal);
            int sl = (t >> 1) & 3;
            mb[sl] = (t & 1) ? (mb[sl] | (m << 16)) : m;
            if ((t & 7) == 7 && lane == 0)
                *(uint4*)(&sh[sub * 128 + (t & ~7)]) = make_uint4(mb[0], mb[1], mb[2], mb[3]);
            sp = dyn_step(w, u, v, rf);
        }
        if (tb < 7) {
#pragma unroll
            for (int i = 0; i < 4; ++i) cur[i] = nxt[i];
        }
    }
    __syncthreads();
    // mb1 epilogue: 128 t x 12 y rows for this (b,oc)
    for (int idx = tid; idx < 1536; idx += 576) {
        int t = idx / 12, y = idx % 12;
        int Q0 = y * 12;
        int w0 = Q0 >> 4, off = Q0 & 15;
        unsigned int v0 = sh[w0 * 128 + t];
        unsigned int v1 = (off > 4) ? (unsigned int)sh[(w0 + 1) * 128 + t] : 0u;
        unsigned int m = ((v0 >> off) | (v1 << (16 - off))) & 0xFFFu;
        size_t rowb = (size_t)(t * 48 + b) * 14;
        pb16[(rowb + y + 1) * 8 + oc] = (unsigned short)(m << 1);
        if (y == 0)  pb16[rowb * 8 + oc] = 0;
        if (y == 11) pb16[(rowb + 13) * 8 + oc] = 0;
    }
}

// ---------------------------------------------------------------------------
// k_wsum2: conv2 wsum (8->16ch, 3x3, 12->12), oc-quad vectorized.
// Pair 6-bit windows -> float4 LUT over the oc quad: tbl4[(pr*3+ky)*71+idx]
// (13.6 KB). Block = (b, ocg, tch): 576 thr = 4 tq x 144 pix; one thread =
// one pixel, 4 oc, 8 t. Grid 768 = 48b x 4ocg x 4tch. T16-tiled output.
// ---------------------------------------------------------------------------
__global__ __launch_bounds__(576) void k_wsum2(const unsigned short* __restrict__ pb16,
                                               const float* __restrict__ w2,
                                               float* __restrict__ ws) {
    __shared__ float wsh[288];
    __shared__ ffrag tbl4[852];           // [4pr][3ky][71] float4 (13.6 KB)
    int tid = threadIdx.x;
    int tch = blockIdx.x & 3;
    int r = blockIdx.x >> 2;
    int ocg = r & 3; int b = r >> 2;      // b 0..47, ocg 0..3
    if (tid < 288) wsh[tid] = w2[(ocg * 4 + tid / 72) * 72 + (tid % 72)];
    __syncthreads();
    for (int e = tid; e < 852; e += 576) {
        int pr = e / 213;                 // 3*71
        int rem = e % 213;
        int ky = rem / 71;
        int idx = rem % 71;
        int lo = idx % 9, hi = idx / 9;   // valid windows have lo<8, hi<8
        ffrag val = {0.f, 0.f, 0.f, 0.f};
#pragma unroll
        for (int oc4 = 0; oc4 < 4; ++oc4) {
            float a = 0.f;
#pragma unroll
            for (int k = 0; k < 3; ++k)
                a += ((lo >> k) & 1) ? wsh[oc4 * 72 + (2 * pr) * 9 + ky * 3 + k] : 0.f;
#pragma unroll
            for (int k = 0; k < 3; ++k)
                a += ((hi >> k) & 1) ? wsh[oc4 * 72 + (2 * pr + 1) * 9 + ky * 3 + k] : 0.f;
            val[oc4] = a;
        }
        tbl4[(pr * 3 + ky) * 71 + idx] = val;
    }
    __syncthreads();
    int tq = tid / 144;
    int pix = tid % 144;
    int q = pix >> 2, s = pix & 3;
    int ox = (q % 6) * 2 + (s & 1);
    int oy = (q / 6) * 2 + (s >> 1);
    int t0 = tch * 32 + tq * 8;
    ffrag acc[8];
#pragma unroll
    for (int j = 0; j < 8; ++j) {
        int t = t0 + j;
        ffrag a = {0.f, 0.f, 0.f, 0.f};
        if (t > 0) {
            const uint4* rp = (const uint4*)(pb16 + (((size_t)(t - 1) * 48 + b) * 14 + oy) * 8);
#pragma unroll
            for (int ky = 0; ky < 3; ++ky) {
                uint4 row = rp[ky];
                unsigned int wd[4] = {row.x, row.y, row.z, row.w};
#pragma unroll
                for (int pr = 0; pr < 4; ++pr) {
                    unsigned int lo = (wd[pr] >> ox) & 7u;
                    unsigned int hi = (wd[pr] >> (16 + ox)) & 7u;
                    a += tbl4[(pr * 3 + ky) * 71 + (int)(lo + 9u * hi)];
                }
            }
        }
        acc[j] = a;
    }
    size_t tilebase = (size_t)(t0 >> 4) * 1769472 + (t0 & 15);
#pragma unroll
    for (int oc4 = 0; oc4 < 4; ++oc4) {
        int neuron = (b * 16 + ocg * 4 + oc4) * 144 + pix;
        float* wp = ws + tilebase + (size_t)neuron * 16;
        *(float4*)(wp)     = make_float4(acc[0][oc4], acc[1][oc4], acc[2][oc4], acc[3][oc4]);
        *(float4*)(wp + 4) = make_float4(acc[4][oc4], acc[5][oc4], acc[6][oc4], acc[7][oc4]);
    }
}

// ---------------------------------------------------------------------------
// k_scan2: conv2 LIF + pool2 LIF + mb2 epilogue. Block 576 = 4 images
// (9 waves); wave = 16 quads. Spike words -> LDS sh[wloc][t]; after barrier
// block writes pb2 rows (6 bits <<1) + pads for its 4 images. Grid 192.
// ---------------------------------------------------------------------------
__global__ __launch_bounds__(576) void k_scan2(const float* __restrict__ ws,
                                               unsigned short* __restrict__ pb2) {
    __shared__ unsigned short sh[9 * 128];
    int tid = threadIdx.x;
    int wloc = tid >> 6, lane = tid & 63;
    int g4 = blockIdx.x;                  // 0..191
    const float* bp = ws + (size_t)(g4 * 576 + tid) * 16;
    float u = 0.f, v = 0.f, rf = 0.f;
    float pu = 0.f, pv = 0.f, prf = 0.f;
    float sp = 0.f;
    unsigned int mb[4];
    float4 cur[4], nxt[4];
#pragma unroll
    for (int i = 0; i < 4; ++i) cur[i] = *(const float4*)(bp + i * 4);
    for (int tb = 0; tb < 8; ++tb) {
        if (tb < 7) {
            const float* np = bp + (size_t)(tb + 1) * 1769472;
#pragma unroll
            for (int i = 0; i < 4; ++i) nxt[i] = *(const float4*)(np + i * 4);
        }
#pragma unroll
        for (int j = 0; j < 16; ++j) {
            int t = tb * 16 + j;
            float w = f4_elem(cur[j >> 2], j & 3);
            float cnt = dpp_add_xor2(dpp_add_xor1(sp));
            float ps = dyn_step(88.0f * cnt, pu, pv, prf);
            unsigned long long bal = __ballot(((lane & 3) == 0) && (ps > 0.5f));
            unsigned int m = compress4(bal);
            int sl = (t >> 1) & 3;
            mb[sl] = (t & 1) ? (mb[sl] | (m << 16)) : m;
            if ((t & 7) == 7 && lane == 0)
                *(uint4*)(&sh[wloc * 128 + (t & ~7)]) = make_uint4(mb[0], mb[1], mb[2], mb[3]);
            sp = dyn_step(w, u, v, rf);
        }
        if (tb < 7) {
#pragma unroll
            for (int i = 0; i < 4; ++i) cur[i] = nxt[i];
        }
    }
    __syncthreads();
    // mb2 epilogue: 128 t x 4 images x 6 y rows
    for (int idx = tid; idx < 3072; idx += 576) {
        int t = idx / 24;
        int r2 = idx % 24;
        int lI = r2 / 6, y = r2 % 6;
        int img = g4 * 4 + lI;
        int b = img >> 4, oc = img & 15;
        int Q0 = lI * 36 + y * 6;
        int w0 = Q0 >> 4, off = Q0 & 15;
        unsigned int v0 = sh[w0 * 128 + t];
        unsigned int v1 = (off > 10) ? (unsigned int)sh[(w0 + 1) * 128 + t] : 0u;
        unsigned int m = ((v0 >> off) | (v1 << (16 - off))) & 0x3Fu;
        size_t rowb = (size_t)(t * 48 + b) * 8;
        pb2[(rowb + y + 1) * 16 + oc] = (unsigned short)(m << 1);
        if (y == 0) pb2[rowb * 16 + oc] = 0;
        if (y == 5) pb2[(rowb + 7) * 16 + oc] = 0;
    }
}

// ---------------------------------------------------------------------------
// k_wsum3: conv3 wsum (16->32ch, 3x3, 6->6), oc-quad vectorized.
// Pair 6-bit windows -> float4 LUT over the oc quad: tbl4[(pr*3+ky)*71+idx]
// (8 pr, 27.3 KB). Block = (ocg, bg, tch): 576 thr = 4 bsel x 36 pix x 4 tq;
// one thread = one pixel, 4 oc, 4 t. tq innermost -> 4-lane groups write
// full 64B sectors. Grid 768 = 8ocg x 12bg x 8tch. T16-tiled output.
// ---------------------------------------------------------------------------
__global__ __launch_bounds__(576) void k_wsum3(const unsigned short* __restrict__ pb2,
                                               const float* __restrict__ w3,
                                               float* __restrict__ ws) {
    __shared__ float wsh[576];
    __shared__ ffrag tbl4[1704];          // [8pr][3ky][71] float4 (27.3 KB)
    int tid = threadIdx.x;
    int tch = blockIdx.x & 7;
    int gb = blockIdx.x >> 3;             // 0..95 = ocg*12 + bg
    int ocg = gb / 12, bg = gb % 12;
    wsh[tid] = w3[(ocg * 4 + tid / 144) * 144 + (tid % 144)];
    __syncthreads();
    for (int e = tid; e < 1536; e += 576) {
        int pr = e / 192;                 // 0..7
        int ky = (e / 64) % 3;
        int i = e & 63;
        int lo = i & 7, hi = i >> 3;
        ffrag val = {0.f, 0.f, 0.f, 0.f};
#pragma unroll
        for (int oc4 = 0; oc4 < 4; ++oc4) {
            float a = 0.f;
#pragma unroll
            for (int k = 0; k < 3; ++k)
                a += ((lo >> k) & 1) ? wsh[oc4 * 144 + (2 * pr) * 9 + ky * 3 + k] : 0.f;
#pragma unroll
            for (int k = 0; k < 3; ++k)
                a += ((hi >> k) & 1) ? wsh[oc4 * 144 + (2 * pr + 1) * 9 + ky * 3 + k] : 0.f;
            val[oc4] = a;
        }
        tbl4[(pr * 3 + ky) * 71 + lo + 9 * hi] = val;
    }
    __syncthreads();
    int tq = tid & 3;
    int r = tid >> 2;                     // 0..143
    int pix = r % 36;
    int bsel = r / 36;                    // 0..3
    int q = pix >> 2, s = pix & 3;
    int ox = (q % 3) * 2 + (s & 1);
    int oy = (q / 3) * 2 + (s >> 1);
    int b = bg * 4 + bsel;
    int t0 = tch * 16 + tq * 4;
    ffrag acc[4];
#pragma unroll
    for (int j = 0; j < 4; ++j) {
        int t = t0 + j;
        ffrag a = {0.f, 0.f, 0.f, 0.f};
        if (t > 0) {
            const uint4* rp = (const uint4*)(pb2 + (((size_t)(t - 1) * 48 + b) * 8 + oy) * 16);
#pragma unroll
            for (int ky = 0; ky < 3; ++ky) {
                uint4 rA = rp[ky * 2];
                uint4 rB = rp[ky * 2 + 1];
                unsigned int wd[8] = {rA.x, rA.y, rA.z, rA.w, rB.x, rB.y, rB.z, rB.w};
#pragma unroll
                for (int pr = 0; pr < 8; ++pr) {
                    unsigned int lo = (wd[pr] >> ox) & 7u;
                    unsigned int hi = (wd[pr] >> (16 + ox)) & 7u;
                    a += tbl4[(pr * 3 + ky) * 71 + (int)(lo + 9u * hi)];
                }
            }
        }
        acc[j] = a;
    }
    size_t base = (size_t)tch * 884736;
#pragma unroll
    for (int oc4 = 0; oc4 < 4; ++oc4) {
        int neuron = (b * 32 + ocg * 4 + oc4) * 36 + pix;
        float* wp = ws + base + (size_t)neuron * 16 + tq * 4;
        *(float4*)(wp) = make_float4(acc[0][oc4], acc[1][oc4], acc[2][oc4], acc[3][oc4]);
    }
}

// ---------------------------------------------------------------------------
// k_scan3: conv3 LIF + pool3 LIF + mb3 epilogue. Block 256 = 4 waves
// covering G range [blockIdx*64, +64). Spike words -> LDS sh[wloc][t]; after
// barrier block writes a3 bf16 rows (t+1, delay-shift folded) + zeroes its
// slice of row 0. Grid 216.
// ---------------------------------------------------------------------------
__global__ __launch_bounds__(256) void k_scan3(const float* __restrict__ ws,
                                               unsigned short* __restrict__ a3) {
    __shared__ unsigned short sh[4 * 128];
    int tid = threadIdx.x;
    int wloc = tid >> 6, lane = tid & 63;
    int wv = blockIdx.x * 4 + wloc;       // 0..863
    const float* bp = ws + (size_t)(wv * 64 + lane) * 16;
    float u = 0.f, v = 0.f, rf = 0.f;
    float pu = 0.f, pv = 0.f, prf = 0.f;
    float sp = 0.f;
    unsigned int mb[4];
    float4 cur[4], nxt[4];
#pragma unroll
    for (int i = 0; i < 4; ++i) cur[i] = *(const float4*)(bp + i * 4);
    for (int tb = 0; tb < 8; ++tb) {
        if (tb < 7) {
            const float* np = bp + (size_t)(tb + 1) * 884736;
#pragma unroll
            for (int i = 0; i < 4; ++i) nxt[i] = *(const float4*)(np + i * 4);
        }
#pragma unroll
        for (int j = 0; j < 16; ++j) {
            int t = tb * 16 + j;
            float w = f4_elem(cur[j >> 2], j & 3);
            float cnt = dpp_add_xor2(dpp_add_xor1(sp));
            float ps = dyn_step(88.0f * cnt, pu, pv, prf);
            unsigned long long bal = __ballot(((lane & 3) == 0) && (ps > 0.5f));
            unsigned int m = compress4(bal);
            int sl = (t >> 1) & 3;
            mb[sl] = (t & 1) ? (mb[sl] | (m << 16)) : m;
            if ((t & 7) == 7 && lane == 0)
                *(uint4*)(&sh[wloc * 128 + (t & ~7)]) = make_uint4(mb[0], mb[1], mb[2], mb[3]);
            sp = dyn_step(w, u, v, rf);
        }
        if (tb < 7) {
#pragma unroll
            for (int i = 0; i < 4; ++i) cur[i] = nxt[i];
        }
    }
    __syncthreads();
    // mb3 epilogue: G slice [blockIdx*64, +64), rows t+1 for t in [0,127)
    int G0 = blockIdx.x * 64;
    int g = tid & 63, tq = tid >> 6;
    if (tq == 0) a3[G0 + g] = 0;          // row 0 (delay-shift zero)
    for (int t = tq; t < 127; t += 4) {
        unsigned int bit = ((unsigned int)sh[(g >> 4) * 128 + t] >> (g & 15)) & 1u;
        a3[(size_t)(t + 1) * 13824 + G0 + g] = bit ? 0x3F80 : 0;
    }
}

// ---------------------------------------------------------------------------
// k_fc1mm: wsf1[m][o] = A x W via mfma_f32_16x16x32_bf16. Linear coalesced
// epilogue (wsf1[m*512+n]). Bs staging reads transposed wbT[512][864].
// ---------------------------------------------------------------------------
__global__ __launch_bounds__(256) void k_fc1mm(const unsigned short* __restrict__ a3,
                                               const unsigned short* __restrict__ wb,
                                               float* __restrict__ wsf1) {
    __shared__ unsigned short Bs[16 * 872];
    int tid = threadIdx.x;
    int nt = blockIdx.x & 31;
    int mc = blockIdx.x >> 5;
    int n0 = nt * 16;
    for (int idx = tid; idx < 13824; idx += 256) {
        int n = idx / 864;
        int kp = idx % 864;
        Bs[n * 872 + kp] = wb[(size_t)(n0 + n) * 864 + kp];
    }
    __syncthreads();
    int wave = tid >> 6;
    int lane = tid & 63;
    int ln = lane & 15, quad = lane >> 4;
#pragma unroll
    for (int i = 0; i < 4; ++i) {
        int m0 = (mc * 16 + wave * 4 + i) * 16;
        const unsigned short* arow = a3 + (size_t)(m0 + ln) * 288 + quad * 8;
        ffrag acc = {0.f, 0.f, 0.f, 0.f};
#pragma unroll
        for (int kb = 0; kb < 9; ++kb) {
            bfrag av = *(const bfrag*)(arow + kb * 32);
#pragma unroll
            for (int c = 0; c < 3; ++c) {
                bfrag bv = *(const bfrag*)(&Bs[ln * 872 + c * 288 + kb * 32 + quad * 8]);
                acc = __builtin_amdgcn_mfma_f32_16x16x32_bf16(av, bv, acc, 0, 0, 0);
            }
        }
        float* wout = wsf1 + (size_t)(m0 + quad * 4) * 512 + n0 + ln;
        wout[0] = acc[0];
        wout[512] = acc[1];
        wout[1024] = acc[2];
        wout[1536] = acc[3];
    }
}

// k_fc1s: fc1 LIF scan, linear strided reads + 16-deep prefetch.
__global__ __launch_bounds__(256) void k_fc1s(const float* __restrict__ wsf1,
                                              float* __restrict__ f1f) {
    int tid = blockIdx.x * 256 + threadIdx.x;   // 0..24575
    float u = 0.f, v = 0.f, rf = 0.f;
    float wbuf[16];
#pragma unroll
    for (int i = 0; i < 16; ++i) wbuf[i] = wsf1[(size_t)i * 24576 + tid];
    for (int tb = 0; tb < 128; tb += 16) {
#pragma unroll
        for (int j = 0; j < 16; ++j) {
            int t = tb + j;
            float w = wbuf[j];
            if (t + 16 < 128) wbuf[j] = wsf1[(size_t)(t + 16) * 24576 + tid];
            float s = dyn_step(w, u, v, rf);
            f1f[(size_t)t * 24576 + tid] = s;
        }
    }
}

// k_fc2w: fc2 wsum, parallel over t. Wave per (t,b).
__global__ __launch_bounds__(256) void k_fc2w(const float* __restrict__ f1f,
                                              const float* __restrict__ wfc2,
                                              float* __restrict__ wsf2) {
    int wv = blockIdx.x * 4 + (threadIdx.x >> 6);   // 0..6143
    int lane = threadIdx.x & 63;
    int b = wv % 48, t = wv / 48;
    int o = lane & 1, kq = lane >> 1;
    float acc = 0.f;
    if (t > 0) {
        const float* wp = wfc2 + o * 512 + kq * 16;
        const float* sp = f1f + (size_t)(t - 1) * 24576 + b * 512 + kq * 16;
#pragma unroll
        for (int i = 0; i < 16; ++i) acc += wp[i] * sp[i];
    }
#pragma unroll
    for (int m = 2; m < 64; m <<= 1) acc += __shfl_xor(acc, m, 64);
    if (lane < 2) wsf2[(size_t)t * 96 + b * 2 + o] = acc;
}

// k_fc2s: fc2 LIF scan + delay-shift into out [B,2,T]. 96 active threads.
__global__ __launch_bounds__(128) void k_fc2s(const float* __restrict__ wsf2,
                                              float* __restrict__ out) {
    int tid = threadIdx.x;
    if (tid >= 96) return;
    float* ob = out + tid * 128;       // tid = b*2+o
    ob[0] = 0.0f;
    float u = 0.f, v = 0.f, rf = 0.f;
    float wbuf[8];
#pragma unroll
    for (int i = 0; i < 8; ++i) wbuf[i] = wsf2[(size_t)i * 96 + tid];
    for (int tb = 0; tb < 128; tb += 8) {
#pragma unroll
        for (int j = 0; j < 8; ++j) {
            int t = tb + j;
            float w = wbuf[j];
            if (t + 8 < 128) wbuf[j] = wsf2[(size_t)(t + 8) * 96 + tid];
            float s = dyn_step(w, u, v, rf);
            if (t < 127) ob[t + 1] = s;
        }
    }
}

// ---------------------------------------------------------------------------
extern "C" void kernel_launch(void* const* d_in, const int* in_sizes, int n_in,
                              void* d_out, int out_size, void* d_ws, size_t ws_size,
                              hipStream_t stream) {
    const float* in   = (const float*)d_in[0];
    const float* w1   = (const float*)d_in[1];
    const float* w2   = (const float*)d_in[2];
    const float* w3   = (const float*)d_in[3];
    const float* wfc1 = (const float*)d_in[4];
    const float* wfc2 = (const float*)d_in[5];
    float* out = (float*)d_out;
    char* ws = (char*)d_ws;

    float*          slab = (float*)(ws);                       // 113,246,208 (conv1 2-half slab; conv2/3 use region 0)
    uint2*          xb   = (uint2*)(ws + 113246208);           //  2,752,512
    unsigned short* pb16 = (unsigned short*)(ws + 115998720);  //  1,376,256
    unsigned short* pb2  = (unsigned short*)(ws + 117374976);  //  1,572,864
    float*          f1f  = (float*)(ws + 118947840);           // 12,582,912
    unsigned short* a3   = (unsigned short*)(ws + 131530752);  //  3,538,944 [128][13824] bf16
    unsigned short* wb   = (unsigned short*)(ws + 135069696);  //    884,736 wbT[512][864] bf16
    float*          wsf1 = (float*)(ws);                       // 12,582,912 (slab reuse, post-scan3)
    float*          wsf2 = (float*)(ws + 16777216);            //     49,152 (slab reuse, disjoint)
    // total 135,954,432 bytes (workspace 256 MiB)
    // no memsets — pad rows written by k_masks / scan epilogues

    k_masks   <<<1200, 256, 0, stream>>>(in, wfc1, xb, wb);   // masks + wsplit fold
    k_wsum1   <<<1536, 576, 0, stream>>>(xb, w1, slab);
    k_scan1   <<<384, 576, 0, stream>>>(slab, pb16);          // + mb1 fold
    k_wsum2   <<<768, 576, 0, stream>>>(pb16, w2, slab);
    k_scan2   <<<192, 576, 0, stream>>>(slab, pb2);           // + mb2 fold
    k_wsum3   <<<768, 576, 0, stream>>>(pb2, w3, slab);
    k_scan3   <<<216, 256, 0, stream>>>(slab, a3);            // + mb3 fold
    k_fc1mm   <<<768, 256, 0, stream>>>(a3, wb, wsf1);
    k_fc1s    <<<96, 256, 0, stream>>>(wsf1, f1f);
    k_fc2w    <<<1536, 256, 0, stream>>>(f1f, wfc2, wsf2);
    k_fc2s    <<<1, 128, 0, stream>>>(wsf2, out);
}